// Round 1
// baseline (15652.977 us; speedup 1.0000x reference)
//
#include <hip/hip_runtime.h>

// FixedPtSQP: 1024 independent SQP solves, N=64, M_IN=128 (G=[I;-I]), M_EQ=1 (A=1^T).
// One wave (64 lanes) per batch element; lane i owns row i of H=Q+diag(dd) in registers.
// KKT solved via Cholesky + bordered elimination (A = ones row).

__device__ __forceinline__ float wave_sum(float v) {
#pragma unroll
  for (int o = 32; o > 0; o >>= 1) v += __shfl_xor(v, o, 64);
  return v;
}
__device__ __forceinline__ float wave_min(float v) {
#pragma unroll
  for (int o = 32; o > 0; o >>= 1) v = fminf(v, __shfl_xor(v, o, 64));
  return v;
}

__global__ __launch_bounds__(64, 1) void sqp_solve_kernel(
    const float* __restrict__ C, const float* __restrict__ Q,
    float* __restrict__ out) {
  const int b = blockIdx.x;
  const int i = threadIdx.x;  // lane 0..63 == row index

  __shared__ float Lmat[64 * 65];   // L (lower), pad 65 -> conflict-free col reads
  __shared__ float rldiag[64];      // 1/L[k][k]
  __shared__ float colbuf[2][64];   // current Cholesky column, double-buffered
  __shared__ float bcast[64];       // vector broadcast scratch

  // Q row i lives in registers for the whole kernel (shared by all 6 SQP iters)
  float Qrow[64];
#pragma unroll
  for (int j = 0; j < 64; j += 4) {
    const float4 q = *reinterpret_cast<const float4*>(&Q[i * 64 + j]);
    Qrow[j + 0] = q.x; Qrow[j + 1] = q.y; Qrow[j + 2] = q.z; Qrow[j + 3] = q.w;
  }
  const float ci = C[b * 64 + i];

  float x = 0.5f;   // x0
  float d = 0.0f;   // last QP primal step

#pragma unroll 1
  for (int sqp = 0; sqp < 6; ++sqp) {   // MAX_ITER1 + MAX_ITER2, ALPHA=1
    // p = Q0 x - c  (Q0 symmetric => x@Q0 = Q0 x)
    bcast[i] = x;
    __syncthreads();
    float p = -ci;
#pragma unroll
    for (int j = 0; j < 64; ++j) p = fmaf(Qrow[j], bcast[j], p);
    const float h1 = 1.0f - x;
    const float h2 = x;
    const float beq = 1.0f - wave_sum(x);
    __syncthreads();

    // QP state (lane i holds z_i, s/lam halves i and 64+i, nu uniform)
    float z = 0.f, s1 = 1.f, s2 = 1.f, l1 = 1.f, l2 = 1.f, nu = 0.f;

#pragma unroll 1
    for (int it = 0; it < 15; ++it) {   // NEWTON_ITERS
      const float mu = 0.1f * wave_sum(fmaf(s1, l1, s2 * l2)) * (1.0f / 128.0f);

      // Qz matvec via LDS broadcast
      bcast[i] = z;
      __syncthreads();
      float Qz = 0.f;
#pragma unroll
      for (int j = 0; j < 64; ++j) Qz = fmaf(Qrow[j], bcast[j], Qz);

      const float r_dual = Qz + p + (l1 - l2) + nu;      // G^T lam = l1-l2; A^T nu = nu
      const float rp1 = z + s1 - h1;                     // G z = [z; -z]
      const float rp2 = -z + s2 - h2;
      const float r_peq = wave_sum(z) - beq;
      const float rc1 = fmaf(l1, s1, -mu);
      const float rc2 = fmaf(l2, s2, -mu);
      const float dd = l1 / s1 + l2 / s2;                // diag of G^T D G
      const float w1 = (l1 * rp1 - rc1) / s1;
      const float w2 = (l2 * rp2 - rc2) / s2;
      const float rhs = -(r_dual + w1 - w2);             // rhs_z

      // H row i = Q row i + dd at diagonal
      float Hrow[64];
#pragma unroll
      for (int j = 0; j < 64; ++j) Hrow[j] = Qrow[j] + ((j == i) ? dd : 0.0f);

      // In-place right-looking Cholesky; column k = Hrow[k] across lanes i>=k.
#pragma unroll
      for (int k = 0; k < 64; ++k) {
        const float akk = __shfl(Hrow[k], k, 64);
        const float rl = 1.0f / sqrtf(fmaxf(akk, 1e-30f));
        const float lik = Hrow[k] * rl;
        Hrow[k] = lik;                 // L[i][k] (valid for i>=k)
        colbuf[k & 1][i] = lik;
        Lmat[i * 65 + k] = lik;        // persist L for the L^T solve
        if (i == 0) rldiag[k] = rl;
        __syncthreads();
        const float* cb = colbuf[k & 1];
#pragma unroll
        for (int j = k + 1; j < 64; ++j)
          Hrow[j] = fmaf(-lik, cb[j], Hrow[j]);          // trailing rank-1 update
      }
      __syncthreads();

      // Forward solve L a = [rhs, 1] (two RHS fused)
      float a1 = rhs, a2 = 1.0f, y1 = 0.f, y2 = 0.f;
#pragma unroll
      for (int k = 0; k < 64; ++k) {
        const float rl = rldiag[k];
        const float t1 = __shfl(a1, k, 64) * rl;
        const float t2 = __shfl(a2, k, 64) * rl;
        if (i == k) { y1 = t1; y2 = t2; }
        const float lk = (i > k) ? Hrow[k] : 0.0f;       // L[i][k]
        a1 = fmaf(-lk, t1, a1);
        a2 = fmaf(-lk, t2, a2);
      }

      // Backward solve L^T u = y (two RHS); L[k][i] read from LDS (stride-1, no conflicts)
      float u1 = 0.f, u2 = 0.f;
      a1 = y1; a2 = y2;
#pragma unroll
      for (int k = 63; k >= 0; --k) {
        const float rl = rldiag[k];
        const float t1 = __shfl(a1, k, 64) * rl;
        const float t2 = __shfl(a2, k, 64) * rl;
        if (i == k) { u1 = t1; u2 = t2; }
        const float lki = (i < k) ? Lmat[k * 65 + i] : 0.0f;
        a1 = fmaf(-lki, t1, a1);
        a2 = fmaf(-lki, t2, a2);
      }

      // Bordered system: dnu = (1^T u1 + r_peq) / (1^T u2); dz = u1 - dnu*u2
      const float sum1 = wave_sum(u1);
      const float sum2 = wave_sum(u2);
      const float dnu = (sum1 + r_peq) / sum2;
      const float dz = fmaf(-dnu, u2, u1);

      const float dl1 = (l1 * (rp1 + dz) - rc1) / s1;    // G dz = [dz; -dz]
      const float dl2 = (l2 * (rp2 - dz) - rc2) / s2;
      const float ds1 = -rp1 - dz;
      const float ds2 = -rp2 + dz;

      const float c1m = (dl1 < 0.0f) ? (-l1 / dl1) : 1.0f;
      const float c2m = (dl2 < 0.0f) ? (-l2 / dl2) : 1.0f;
      const float c3m = (ds1 < 0.0f) ? (-s1 / ds1) : 1.0f;
      const float c4m = (ds2 < 0.0f) ? (-s2 / ds2) : 1.0f;
      const float am = wave_min(fminf(fminf(c1m, c2m), fminf(c3m, c4m)));
      const float a = 0.99f * fminf(1.0f, am);

      z = fmaf(a, dz, z);
      s1 = fmaf(a, ds1, s1);
      s2 = fmaf(a, ds2, s2);
      l1 = fmaf(a, dl1, l1);
      l2 = fmaf(a, dl2, l2);
      nu = fmaf(a, dnu, nu);
      __syncthreads();   // protect LDS (Lmat/rldiag/bcast) before next iteration rewrites
    }

    x += z;   // ALPHA=1: x += d, lam never read again
    d = z;
  }

  out[b * 64 + i] = x + d;   // reference returns x + d (d added twice overall)
}

extern "C" void kernel_launch(void* const* d_in, const int* in_sizes, int n_in,
                              void* d_out, int out_size, void* d_ws, size_t ws_size,
                              hipStream_t stream) {
  const float* c = (const float*)d_in[0];   // (B, 64) f32
  const float* Q = (const float*)d_in[1];   // (64, 64) f32
  float* out = (float*)d_out;               // (B, 64) f32
  const int B = in_sizes[0] / 64;
  hipLaunchKernelGGL(sqp_solve_kernel, dim3(B), dim3(64), 0, stream, c, Q, out);
}